// Round 5
// baseline (3213.638 us; speedup 1.0000x reference)
//
#include <hip/hip_runtime.h>
#include <math.h>

#define SLOPE 0.2f

// ---------------- CSR build ----------------

__global__ __launch_bounds__(256) void k_count(const int* __restrict__ ei,
                                               int* __restrict__ deg, int E) {
    int base = (blockIdx.x * 256 + threadIdx.x) * 4;
    if (base + 3 < E) {
        int4 d4 = *(const int4*)(ei + E + base);
        atomicAdd(&deg[d4.x], 1);
        atomicAdd(&deg[d4.y], 1);
        atomicAdd(&deg[d4.z], 1);
        atomicAdd(&deg[d4.w], 1);
    } else {
        for (int e = base; e < E; e++) atomicAdd(&deg[ei[E + e]], 1);
    }
}

__global__ __launch_bounds__(256) void k_scan1(const int* __restrict__ deg,
                                               int* __restrict__ rp,
                                               int* __restrict__ blk, int n) {
    __shared__ int sd[256];
    int t = threadIdx.x;
    int base = blockIdx.x * 1024 + t * 4;
    int v0 = 0, v1 = 0, v2 = 0, v3 = 0;
    if (base + 0 < n) v0 = deg[base + 0];
    if (base + 1 < n) v1 = deg[base + 1];
    if (base + 2 < n) v2 = deg[base + 2];
    if (base + 3 < n) v3 = deg[base + 3];
    int s = v0 + v1 + v2 + v3;
    sd[t] = s;
    __syncthreads();
    for (int off = 1; off < 256; off <<= 1) {
        int x = (t >= off) ? sd[t - off] : 0;
        __syncthreads();
        sd[t] += x;
        __syncthreads();
    }
    int ex = sd[t] - s;
    if (t == 255) blk[blockIdx.x] = sd[255];
    if (base + 0 < n) rp[base + 0] = ex; ex += v0;
    if (base + 1 < n) rp[base + 1] = ex; ex += v1;
    if (base + 2 < n) rp[base + 2] = ex; ex += v2;
    if (base + 3 < n) rp[base + 3] = ex;
}

__global__ __launch_bounds__(256) void k_scan2(int* __restrict__ blk, int nblk) {
    __shared__ int sd[256];
    int t = threadIdx.x;
    int v = (t < nblk) ? blk[t] : 0;
    sd[t] = v;
    __syncthreads();
    for (int off = 1; off < 256; off <<= 1) {
        int x = (t >= off) ? sd[t - off] : 0;
        __syncthreads();
        sd[t] += x;
        __syncthreads();
    }
    if (t < nblk) blk[t] = sd[t] - v;
}

__global__ __launch_bounds__(256) void k_scan3(int* __restrict__ rp,
                                               const int* __restrict__ blk,
                                               int* __restrict__ cur, int n) {
    int t = threadIdx.x;
    int base = blockIdx.x * 1024 + t * 4;
    int off = blk[blockIdx.x];
    #pragma unroll
    for (int i = 0; i < 4; i++) {
        int idx = base + i;
        if (idx < n) {
            int v = rp[idx] + off;
            rp[idx] = v;
            cur[idx] = v;
        }
    }
}

__global__ __launch_bounds__(256) void k_scatter(const int* __restrict__ ei,
                                                 int* __restrict__ cur,
                                                 int* __restrict__ col, int E) {
    int base = (blockIdx.x * 256 + threadIdx.x) * 4;
    if (base + 3 < E) {
        int4 s4 = *(const int4*)(ei + base);
        int4 d4 = *(const int4*)(ei + E + base);
        col[atomicAdd(&cur[d4.x], 1)] = s4.x;
        col[atomicAdd(&cur[d4.y], 1)] = s4.y;
        col[atomicAdd(&cur[d4.z], 1)] = s4.z;
        col[atomicAdd(&cur[d4.w], 1)] = s4.w;
    } else {
        for (int e = base; e < E; e++) {
            int s = ei[e];
            int d = ei[E + e];
            col[atomicAdd(&cur[d], 1)] = s;
        }
    }
}

// ---------------- GEMM: xl = in @ Wl, xr = in @ Wr ----------------
// Register-blocked: thread = 4 rows x 16 cols. Block = 128 rows x 128 cols.
// TAIL FIX (round-4 bug): loads are CLAMPED to row n-1 instead of skipped.
// Reading uninitialized xs[] for OOB rows was UB; clang broke the store
// guards and OOB xl stores corrupted the adjacent xr buffer (rows 0..95).

__global__ __launch_bounds__(256) void k_gemm(const float* __restrict__ in,
                                              const float* __restrict__ Wl,
                                              const float* __restrict__ Wr,
                                              float* __restrict__ xl,
                                              float* __restrict__ xr, int n) {
    __shared__ float4 sW[64 * 32];  // [k][jg]: jg<16 -> Wl cols, else Wr
    int t = threadIdx.x;
    for (int i = t; i < 2048; i += 256) {
        int k = i >> 5, jg = i & 31;
        const float* src = (jg < 16) ? (Wl + k * 64 + jg * 4)
                                     : (Wr + k * 64 + (jg - 16) * 4);
        sW[i] = *(const float4*)src;
    }
    __syncthreads();

    int rt = t & 31;   // 32 row tiles of 4 rows
    int ct = t >> 5;   // 8 col tiles of 16 cols (4 jg)
    int row0 = blockIdx.x * 128 + rt * 4;

    float4 acc[4][4];
    #pragma unroll
    for (int r = 0; r < 4; r++)
        #pragma unroll
        for (int j = 0; j < 4; j++) acc[r][j] = make_float4(0.f, 0.f, 0.f, 0.f);

    #pragma unroll
    for (int kt = 0; kt < 64; kt += 16) {
        float xs[4][16];
        #pragma unroll
        for (int r = 0; r < 4; r++) {
            int rr = row0 + r;
            if (rr > n - 1) rr = n - 1;   // clamp: always-valid load, no UB
            const float4* xp = (const float4*)(in + (size_t)rr * 64 + kt);
            #pragma unroll
            for (int q = 0; q < 4; q++) {
                float4 vv = xp[q];
                xs[r][4 * q + 0] = vv.x; xs[r][4 * q + 1] = vv.y;
                xs[r][4 * q + 2] = vv.z; xs[r][4 * q + 3] = vv.w;
            }
        }
        #pragma unroll
        for (int k = 0; k < 16; k++) {
            #pragma unroll
            for (int j = 0; j < 4; j++) {
                float4 w = sW[(kt + k) * 32 + ct * 4 + j];
                #pragma unroll
                for (int r = 0; r < 4; r++) {
                    float xk = xs[r][k];
                    acc[r][j].x += xk * w.x;
                    acc[r][j].y += xk * w.y;
                    acc[r][j].z += xk * w.z;
                    acc[r][j].w += xk * w.w;
                }
            }
        }
    }

    #pragma unroll
    for (int r = 0; r < 4; r++) {
        int row = row0 + r;
        if (row < n) {
            #pragma unroll
            for (int j = 0; j < 4; j++) {
                int jg = ct * 4 + j;
                float* dst = (jg < 16) ? (xl + (size_t)row * 64 + jg * 4)
                                       : (xr + (size_t)row * 64 + (jg - 16) * 4);
                *(float4*)dst = acc[r][j];
            }
        }
    }
}

// ---------------- node kernel: online-softmax GATv2 aggregation ----------------
// One wave per node, lane = h*16 + o. 8-deep gather pipeline; round-1 math.

__global__ __launch_bounds__(256) void k_node(const float* __restrict__ xl,
                                              const float* __restrict__ xr,
                                              const int* __restrict__ rp,
                                              const int* __restrict__ deg,
                                              const int* __restrict__ col,
                                              const float* __restrict__ A,
                                              const float* __restrict__ Bv,
                                              float* __restrict__ outp,
                                              int n, int relu) {
    int lane = threadIdx.x & 63;
    int node = blockIdx.x * 4 + (threadIdx.x >> 6);
    if (node >= n) return;

    float xr_d = xr[(size_t)node * 64 + lane];
    float a_l = A[lane];
    float b_l = Bv[lane];

    int start = rp[node];
    int d = deg[node];

    float m = -INFINITY, den = 0.f, acc = 0.f;
    for (int i = 0; i < d; i += 8) {
        int sidx[8];
        float v[8];
        #pragma unroll
        for (int j = 0; j < 8; j++) {
            int idx = (i + j < d) ? (start + i + j) : start;
            sidx[j] = col[idx];
        }
        #pragma unroll
        for (int j = 0; j < 8; j++)
            v[j] = xl[(size_t)sidx[j] * 64 + lane];
        #pragma unroll
        for (int j = 0; j < 8; j++) {
            if (i + j < d) {  // wave-uniform guard
                float xl_s = v[j];
                float tsum = xl_s + xr_d;
                tsum = (tsum > 0.f) ? tsum : SLOPE * tsum;
                float p = tsum * a_l;
                p += __shfl_xor(p, 1);
                p += __shfl_xor(p, 2);
                p += __shfl_xor(p, 4);
                p += __shfl_xor(p, 8);
                float mnew = fmaxf(m, p);
                float scale = __expf(m - mnew);  // first valid edge: exp(-inf)=0
                float w = __expf(p - mnew);
                den = den * scale + w;
                acc = acc * scale + w * xl_s;
                m = mnew;
            }
        }
    }
    float o = acc / (den + 1e-16f) + b_l;
    if (relu) o = fmaxf(o, 0.f);
    outp[(size_t)node * 64 + lane] = o;
}

// ---------------- launcher ----------------

extern "C" void kernel_launch(void* const* d_in, const int* in_sizes, int n_in,
                              void* d_out, int out_size, void* d_ws, size_t ws_size,
                              hipStream_t stream) {
    const float* x = (const float*)d_in[0];
    const int* ei = (const int*)d_in[1];
    int N = in_sizes[0] / 64;
    int E = in_sizes[1] / 2;

    const float* Wl[3] = {(const float*)d_in[2], (const float*)d_in[6], (const float*)d_in[10]};
    const float* Wr[3] = {(const float*)d_in[3], (const float*)d_in[7], (const float*)d_in[11]};
    const float* Av[3] = {(const float*)d_in[4], (const float*)d_in[8], (const float*)d_in[12]};
    const float* Bv[3] = {(const float*)d_in[5], (const float*)d_in[9], (const float*)d_in[13]};

    char* w = (char*)d_ws;
    auto carve = [&](size_t bytes) {
        void* p = (void*)w;
        w += (bytes + 255) & ~(size_t)255;
        return p;
    };
    float* xl  = (float*)carve((size_t)N * 64 * 4);
    float* xr  = (float*)carve((size_t)N * 64 * 4);
    float* h   = (float*)carve((size_t)N * 64 * 4);
    int*   rp  = (int*)carve((size_t)N * 4);
    int*   deg = (int*)carve((size_t)N * 4);
    int*   cur = (int*)carve((size_t)N * 4);
    int*   col = (int*)carve((size_t)E * 4);
    int*   blk = (int*)carve(256 * 4);

    int nblk1024 = (N + 1023) / 1024;
    int e4_grid = ((E + 3) / 4 + 255) / 256;

    hipMemsetAsync(deg, 0, (size_t)N * 4, stream);
    k_count<<<e4_grid, 256, 0, stream>>>(ei, deg, E);
    k_scan1<<<nblk1024, 256, 0, stream>>>(deg, rp, blk, N);
    k_scan2<<<1, 256, 0, stream>>>(blk, nblk1024);
    k_scan3<<<nblk1024, 256, 0, stream>>>(rp, blk, cur, N);
    k_scatter<<<e4_grid, 256, 0, stream>>>(ei, cur, col, E);

    int gemm_grid = (N + 127) / 128;
    int node_grid = (N + 3) / 4;

    const float* in_l = x;
    for (int l = 0; l < 3; l++) {
        float* out_l = (l == 2) ? (float*)d_out : h;
        int relu = (l < 2) ? 1 : 0;
        k_gemm<<<gemm_grid, 256, 0, stream>>>(in_l, Wl[l], Wr[l], xl, xr, N);
        k_node<<<node_grid, 256, 0, stream>>>(xl, xr, rp, deg, col, Av[l], Bv[l],
                                              out_l, N, relu);
        in_l = h;
    }
}

// Round 6
// 594.373 us; speedup vs baseline: 5.4068x; 5.4068x over previous
//
#include <hip/hip_runtime.h>
#include <math.h>

#define SLOPE 0.2f

// ---------------- CSR build ----------------

__global__ __launch_bounds__(256) void k_count(const int* __restrict__ ei,
                                               int* __restrict__ deg, int E) {
    int base = (blockIdx.x * 256 + threadIdx.x) * 4;
    if (base + 3 < E) {
        int4 d4 = *(const int4*)(ei + E + base);
        atomicAdd(&deg[d4.x], 1);
        atomicAdd(&deg[d4.y], 1);
        atomicAdd(&deg[d4.z], 1);
        atomicAdd(&deg[d4.w], 1);
    } else {
        for (int e = base; e < E; e++) atomicAdd(&deg[ei[E + e]], 1);
    }
}

__global__ __launch_bounds__(256) void k_scan1(const int* __restrict__ deg,
                                               int* __restrict__ rp,
                                               int* __restrict__ blk, int n) {
    __shared__ int sd[256];
    int t = threadIdx.x;
    int base = blockIdx.x * 1024 + t * 4;
    int v0 = 0, v1 = 0, v2 = 0, v3 = 0;
    if (base + 0 < n) v0 = deg[base + 0];
    if (base + 1 < n) v1 = deg[base + 1];
    if (base + 2 < n) v2 = deg[base + 2];
    if (base + 3 < n) v3 = deg[base + 3];
    int s = v0 + v1 + v2 + v3;
    sd[t] = s;
    __syncthreads();
    for (int off = 1; off < 256; off <<= 1) {
        int x = (t >= off) ? sd[t - off] : 0;
        __syncthreads();
        sd[t] += x;
        __syncthreads();
    }
    int ex = sd[t] - s;
    if (t == 255) blk[blockIdx.x] = sd[255];
    if (base + 0 < n) rp[base + 0] = ex; ex += v0;
    if (base + 1 < n) rp[base + 1] = ex; ex += v1;
    if (base + 2 < n) rp[base + 2] = ex; ex += v2;
    if (base + 3 < n) rp[base + 3] = ex;
}

__global__ __launch_bounds__(256) void k_scan2(int* __restrict__ blk, int nblk) {
    __shared__ int sd[256];
    int t = threadIdx.x;
    int v = (t < nblk) ? blk[t] : 0;
    sd[t] = v;
    __syncthreads();
    for (int off = 1; off < 256; off <<= 1) {
        int x = (t >= off) ? sd[t - off] : 0;
        __syncthreads();
        sd[t] += x;
        __syncthreads();
    }
    if (t < nblk) blk[t] = sd[t] - v;
}

__global__ __launch_bounds__(256) void k_scan3(int* __restrict__ rp,
                                               const int* __restrict__ blk,
                                               int* __restrict__ cur, int n) {
    int t = threadIdx.x;
    int base = blockIdx.x * 1024 + t * 4;
    int off = blk[blockIdx.x];
    #pragma unroll
    for (int i = 0; i < 4; i++) {
        int idx = base + i;
        if (idx < n) {
            int v = rp[idx] + off;
            rp[idx] = v;
            cur[idx] = v;
        }
    }
}

__global__ __launch_bounds__(256) void k_scatter(const int* __restrict__ ei,
                                                 int* __restrict__ cur,
                                                 int* __restrict__ col, int E) {
    int base = (blockIdx.x * 256 + threadIdx.x) * 4;
    if (base + 3 < E) {
        int4 s4 = *(const int4*)(ei + base);
        int4 d4 = *(const int4*)(ei + E + base);
        col[atomicAdd(&cur[d4.x], 1)] = s4.x;
        col[atomicAdd(&cur[d4.y], 1)] = s4.y;
        col[atomicAdd(&cur[d4.z], 1)] = s4.z;
        col[atomicAdd(&cur[d4.w], 1)] = s4.w;
    } else {
        for (int e = base; e < E; e++) {
            int s = ei[e];
            int d = ei[E + e];
            col[atomicAdd(&cur[d], 1)] = s;
        }
    }
}

// ---------------- GEMM: xl = in @ Wl, xr = in @ Wr ----------------
// 4 rows x 16 cols per thread; block = 128 rows x 128 cols.
// K-loop stepped by 4 with unroll(1): only float4 xv[4] of x live at a time.
// (Round-5 spill: full kt unroll hoisted 256 floats of xs -> VGPR=256,
//  2.2 GB scratch traffic, VALUBusy 2.8%. unroll(1) is the containment.)

__global__ __launch_bounds__(256) void k_gemm(const float* __restrict__ in,
                                              const float* __restrict__ Wl,
                                              const float* __restrict__ Wr,
                                              float* __restrict__ xl,
                                              float* __restrict__ xr, int n) {
    __shared__ float4 sW[64 * 32];  // [k][jg]: jg<16 -> Wl cols, else Wr
    int t = threadIdx.x;
    for (int i = t; i < 2048; i += 256) {
        int k = i >> 5, jg = i & 31;
        const float* src = (jg < 16) ? (Wl + k * 64 + jg * 4)
                                     : (Wr + k * 64 + (jg - 16) * 4);
        sW[i] = *(const float4*)src;
    }
    __syncthreads();

    int rt = t & 31;   // 32 row tiles of 4 rows
    int ct = t >> 5;   // 8 col tiles of 16 cols (4 jg)
    int row0 = blockIdx.x * 128 + rt * 4;

    const float* rb[4];
    #pragma unroll
    for (int r = 0; r < 4; r++) {
        int rr = row0 + r;
        if (rr > n - 1) rr = n - 1;   // clamp: always-valid load, no UB
        rb[r] = in + (size_t)rr * 64;
    }

    float4 acc[4][4];
    #pragma unroll
    for (int r = 0; r < 4; r++)
        #pragma unroll
        for (int j = 0; j < 4; j++) acc[r][j] = make_float4(0.f, 0.f, 0.f, 0.f);

    #pragma unroll 1
    for (int k0 = 0; k0 < 64; k0 += 4) {
        float4 xv[4];
        #pragma unroll
        for (int r = 0; r < 4; r++) xv[r] = *(const float4*)(rb[r] + k0);
        #pragma unroll
        for (int kk = 0; kk < 4; kk++) {
            #pragma unroll
            for (int j = 0; j < 4; j++) {
                float4 w = sW[(k0 + kk) * 32 + ct * 4 + j];
                #pragma unroll
                for (int r = 0; r < 4; r++) {
                    float xk = (kk == 0) ? xv[r].x : (kk == 1) ? xv[r].y
                             : (kk == 2) ? xv[r].z : xv[r].w;
                    acc[r][j].x += xk * w.x;
                    acc[r][j].y += xk * w.y;
                    acc[r][j].z += xk * w.z;
                    acc[r][j].w += xk * w.w;
                }
            }
        }
    }

    #pragma unroll
    for (int r = 0; r < 4; r++) {
        int row = row0 + r;
        if (row < n) {
            #pragma unroll
            for (int j = 0; j < 4; j++) {
                int jg = ct * 4 + j;
                float* dst = (jg < 16) ? (xl + (size_t)row * 64 + jg * 4)
                                       : (xr + (size_t)row * 64 + (jg - 16) * 4);
                *(float4*)dst = acc[r][j];
            }
        }
    }
}

// ---------------- node kernel: online-softmax GATv2 aggregation ----------------
// One wave per node, lane = h*16 + o. 8-deep gather pipeline; round-1 math.

__global__ __launch_bounds__(256) void k_node(const float* __restrict__ xl,
                                              const float* __restrict__ xr,
                                              const int* __restrict__ rp,
                                              const int* __restrict__ deg,
                                              const int* __restrict__ col,
                                              const float* __restrict__ A,
                                              const float* __restrict__ Bv,
                                              float* __restrict__ outp,
                                              int n, int relu) {
    int lane = threadIdx.x & 63;
    int node = blockIdx.x * 4 + (threadIdx.x >> 6);
    if (node >= n) return;

    float xr_d = xr[(size_t)node * 64 + lane];
    float a_l = A[lane];
    float b_l = Bv[lane];

    int start = rp[node];
    int d = deg[node];

    float m = -INFINITY, den = 0.f, acc = 0.f;
    for (int i = 0; i < d; i += 8) {
        int sidx[8];
        float v[8];
        #pragma unroll
        for (int j = 0; j < 8; j++) {
            int idx = (i + j < d) ? (start + i + j) : start;
            sidx[j] = col[idx];
        }
        #pragma unroll
        for (int j = 0; j < 8; j++)
            v[j] = xl[(size_t)sidx[j] * 64 + lane];
        #pragma unroll
        for (int j = 0; j < 8; j++) {
            if (i + j < d) {  // wave-uniform guard
                float xl_s = v[j];
                float tsum = xl_s + xr_d;
                tsum = (tsum > 0.f) ? tsum : SLOPE * tsum;
                float p = tsum * a_l;
                p += __shfl_xor(p, 1);
                p += __shfl_xor(p, 2);
                p += __shfl_xor(p, 4);
                p += __shfl_xor(p, 8);
                float mnew = fmaxf(m, p);
                float scale = __expf(m - mnew);  // first valid edge: exp(-inf)=0
                float w = __expf(p - mnew);
                den = den * scale + w;
                acc = acc * scale + w * xl_s;
                m = mnew;
            }
        }
    }
    float o = acc / (den + 1e-16f) + b_l;
    if (relu) o = fmaxf(o, 0.f);
    outp[(size_t)node * 64 + lane] = o;
}

// ---------------- launcher ----------------

extern "C" void kernel_launch(void* const* d_in, const int* in_sizes, int n_in,
                              void* d_out, int out_size, void* d_ws, size_t ws_size,
                              hipStream_t stream) {
    const float* x = (const float*)d_in[0];
    const int* ei = (const int*)d_in[1];
    int N = in_sizes[0] / 64;
    int E = in_sizes[1] / 2;

    const float* Wl[3] = {(const float*)d_in[2], (const float*)d_in[6], (const float*)d_in[10]};
    const float* Wr[3] = {(const float*)d_in[3], (const float*)d_in[7], (const float*)d_in[11]};
    const float* Av[3] = {(const float*)d_in[4], (const float*)d_in[8], (const float*)d_in[12]};
    const float* Bv[3] = {(const float*)d_in[5], (const float*)d_in[9], (const float*)d_in[13]};

    char* w = (char*)d_ws;
    auto carve = [&](size_t bytes) {
        void* p = (void*)w;
        w += (bytes + 255) & ~(size_t)255;
        return p;
    };
    float* xl  = (float*)carve((size_t)N * 64 * 4);
    float* xr  = (float*)carve((size_t)N * 64 * 4);
    float* h   = (float*)carve((size_t)N * 64 * 4);
    int*   rp  = (int*)carve((size_t)N * 4);
    int*   deg = (int*)carve((size_t)N * 4);
    int*   cur = (int*)carve((size_t)N * 4);
    int*   col = (int*)carve((size_t)E * 4);
    int*   blk = (int*)carve(256 * 4);

    int nblk1024 = (N + 1023) / 1024;
    int e4_grid = ((E + 3) / 4 + 255) / 256;

    hipMemsetAsync(deg, 0, (size_t)N * 4, stream);
    k_count<<<e4_grid, 256, 0, stream>>>(ei, deg, E);
    k_scan1<<<nblk1024, 256, 0, stream>>>(deg, rp, blk, N);
    k_scan2<<<1, 256, 0, stream>>>(blk, nblk1024);
    k_scan3<<<nblk1024, 256, 0, stream>>>(rp, blk, cur, N);
    k_scatter<<<e4_grid, 256, 0, stream>>>(ei, cur, col, E);

    int gemm_grid = (N + 127) / 128;
    int node_grid = (N + 3) / 4;

    const float* in_l = x;
    for (int l = 0; l < 3; l++) {
        float* out_l = (l == 2) ? (float*)d_out : h;
        int relu = (l < 2) ? 1 : 0;
        k_gemm<<<gemm_grid, 256, 0, stream>>>(in_l, Wl[l], Wr[l], xl, xr, N);
        k_node<<<node_grid, 256, 0, stream>>>(xl, xr, rp, deg, col, Av[l], Bv[l],
                                              out_l, N, relu);
        in_l = h;
    }
}

// Round 7
// 544.058 us; speedup vs baseline: 5.9068x; 1.0925x over previous
//
#include <hip/hip_runtime.h>
#include <math.h>

#define SLOPE 0.2f
#define LOG2E 1.4426950408889634f

// DPP add over 16-lane head group (row = 16 lanes on CDNA):
// 0xB1 quad_perm xor1, 0x4E quad_perm xor2,
// 0x141 row_half_mirror (xor7: quad0<->1, quad2<->3), 0x140 row_mirror (xor15).
#define DPP_ADD(x, ctrl) \
    ((x) + __int_as_float(__builtin_amdgcn_update_dpp( \
        0, __float_as_int(x), (ctrl), 0xF, 0xF, true)))

// ---------------- CSR build ----------------

__global__ __launch_bounds__(256) void k_count(const int* __restrict__ ei,
                                               int* __restrict__ deg, int E) {
    int base = (blockIdx.x * 256 + threadIdx.x) * 4;
    if (base + 3 < E) {
        int4 d4 = *(const int4*)(ei + E + base);
        atomicAdd(&deg[d4.x], 1);
        atomicAdd(&deg[d4.y], 1);
        atomicAdd(&deg[d4.z], 1);
        atomicAdd(&deg[d4.w], 1);
    } else {
        for (int e = base; e < E; e++) atomicAdd(&deg[ei[E + e]], 1);
    }
}

__global__ __launch_bounds__(256) void k_scan1(const int* __restrict__ deg,
                                               int* __restrict__ rp,
                                               int* __restrict__ blk, int n) {
    __shared__ int sd[256];
    int t = threadIdx.x;
    int base = blockIdx.x * 1024 + t * 4;
    int v0 = 0, v1 = 0, v2 = 0, v3 = 0;
    if (base + 0 < n) v0 = deg[base + 0];
    if (base + 1 < n) v1 = deg[base + 1];
    if (base + 2 < n) v2 = deg[base + 2];
    if (base + 3 < n) v3 = deg[base + 3];
    int s = v0 + v1 + v2 + v3;
    sd[t] = s;
    __syncthreads();
    for (int off = 1; off < 256; off <<= 1) {
        int x = (t >= off) ? sd[t - off] : 0;
        __syncthreads();
        sd[t] += x;
        __syncthreads();
    }
    int ex = sd[t] - s;
    if (t == 255) blk[blockIdx.x] = sd[255];
    if (base + 0 < n) rp[base + 0] = ex; ex += v0;
    if (base + 1 < n) rp[base + 1] = ex; ex += v1;
    if (base + 2 < n) rp[base + 2] = ex; ex += v2;
    if (base + 3 < n) rp[base + 3] = ex;
}

__global__ __launch_bounds__(256) void k_scan2(int* __restrict__ blk, int nblk) {
    __shared__ int sd[256];
    int t = threadIdx.x;
    int v = (t < nblk) ? blk[t] : 0;
    sd[t] = v;
    __syncthreads();
    for (int off = 1; off < 256; off <<= 1) {
        int x = (t >= off) ? sd[t - off] : 0;
        __syncthreads();
        sd[t] += x;
        __syncthreads();
    }
    if (t < nblk) blk[t] = sd[t] - v;
}

__global__ __launch_bounds__(256) void k_scan3(int* __restrict__ rp,
                                               const int* __restrict__ blk,
                                               int* __restrict__ cur, int n) {
    int t = threadIdx.x;
    int base = blockIdx.x * 1024 + t * 4;
    int off = blk[blockIdx.x];
    #pragma unroll
    for (int i = 0; i < 4; i++) {
        int idx = base + i;
        if (idx < n) {
            int v = rp[idx] + off;
            rp[idx] = v;
            cur[idx] = v;
        }
    }
}

__global__ __launch_bounds__(256) void k_scatter(const int* __restrict__ ei,
                                                 int* __restrict__ cur,
                                                 int* __restrict__ col, int E) {
    int base = (blockIdx.x * 256 + threadIdx.x) * 4;
    if (base + 3 < E) {
        int4 s4 = *(const int4*)(ei + base);
        int4 d4 = *(const int4*)(ei + E + base);
        col[atomicAdd(&cur[d4.x], 1)] = s4.x;
        col[atomicAdd(&cur[d4.y], 1)] = s4.y;
        col[atomicAdd(&cur[d4.z], 1)] = s4.z;
        col[atomicAdd(&cur[d4.w], 1)] = s4.w;
    } else {
        for (int e = base; e < E; e++) {
            int s = ei[e];
            int d = ei[E + e];
            col[atomicAdd(&cur[d], 1)] = s;
        }
    }
}

// ---------------- GEMM: xl = in @ Wl, xr = in @ Wr ----------------
// 4 rows x 16 cols per thread; block = 128 rows x 128 cols.
// K stepped by 4, unroll(1) (round-5 spill containment) + 2-stage xv prefetch.

__global__ __launch_bounds__(256) void k_gemm(const float* __restrict__ in,
                                              const float* __restrict__ Wl,
                                              const float* __restrict__ Wr,
                                              float* __restrict__ xl,
                                              float* __restrict__ xr, int n) {
    __shared__ float4 sW[64 * 32];  // [k][jg]: jg<16 -> Wl cols, else Wr
    int t = threadIdx.x;
    for (int i = t; i < 2048; i += 256) {
        int k = i >> 5, jg = i & 31;
        const float* src = (jg < 16) ? (Wl + k * 64 + jg * 4)
                                     : (Wr + k * 64 + (jg - 16) * 4);
        sW[i] = *(const float4*)src;
    }
    __syncthreads();

    int rt = t & 31;   // 32 row tiles of 4 rows
    int ct = t >> 5;   // 8 col tiles of 16 cols (4 jg)
    int row0 = blockIdx.x * 128 + rt * 4;

    const float* rb[4];
    #pragma unroll
    for (int r = 0; r < 4; r++) {
        int rr = row0 + r;
        if (rr > n - 1) rr = n - 1;   // clamp: always-valid load, no UB
        rb[r] = in + (size_t)rr * 64;
    }

    float4 acc[4][4];
    #pragma unroll
    for (int r = 0; r < 4; r++)
        #pragma unroll
        for (int j = 0; j < 4; j++) acc[r][j] = make_float4(0.f, 0.f, 0.f, 0.f);

    auto compute = [&](const float4 (&xv)[4], int k0) {
        #pragma unroll
        for (int kk = 0; kk < 4; kk++) {
            #pragma unroll
            for (int j = 0; j < 4; j++) {
                float4 w = sW[(k0 + kk) * 32 + ct * 4 + j];
                #pragma unroll
                for (int r = 0; r < 4; r++) {
                    float xk = (kk == 0) ? xv[r].x : (kk == 1) ? xv[r].y
                             : (kk == 2) ? xv[r].z : xv[r].w;
                    acc[r][j].x += xk * w.x;
                    acc[r][j].y += xk * w.y;
                    acc[r][j].z += xk * w.z;
                    acc[r][j].w += xk * w.w;
                }
            }
        }
    };

    float4 xv[4];
    #pragma unroll
    for (int r = 0; r < 4; r++) xv[r] = *(const float4*)(rb[r]);
    #pragma unroll 1
    for (int k0 = 0; k0 < 60; k0 += 4) {
        float4 xn[4];
        #pragma unroll
        for (int r = 0; r < 4; r++) xn[r] = *(const float4*)(rb[r] + k0 + 4);
        compute(xv, k0);
        #pragma unroll
        for (int r = 0; r < 4; r++) xv[r] = xn[r];
    }
    compute(xv, 60);

    #pragma unroll
    for (int r = 0; r < 4; r++) {
        int row = row0 + r;
        if (row < n) {
            #pragma unroll
            for (int j = 0; j < 4; j++) {
                int jg = ct * 4 + j;
                float* dst = (jg < 16) ? (xl + (size_t)row * 64 + jg * 4)
                                       : (xr + (size_t)row * 64 + (jg - 16) * 4);
                *(float4*)dst = acc[r][j];
            }
        }
    }
}

// ---------------- node kernel: batch-max online-softmax GATv2 ----------------
// One wave per node, lane = h*16 + o. 8-deep gather pipeline.
// Batch-of-8 softmax: 8 independent logits, one max tree, ONE rescale per
// batch (invalid edges get p=-inf -> w=0, so no per-edge guard).
// 16-lane logit reduce is all-DPP (no DS pipe). exp2 domain (log2e in a_l).

__global__ __launch_bounds__(256) void k_node(const float* __restrict__ xl,
                                              const float* __restrict__ xr,
                                              const int* __restrict__ rp,
                                              const int* __restrict__ deg,
                                              const int* __restrict__ col,
                                              const float* __restrict__ A,
                                              const float* __restrict__ Bv,
                                              float* __restrict__ outp,
                                              int n, int relu) {
    int lane = threadIdx.x & 63;
    int node = blockIdx.x * 4 + (threadIdx.x >> 6);
    if (node >= n) return;

    float xr_d = xr[(size_t)node * 64 + lane];
    float a_l = A[lane] * LOG2E;
    float b_l = Bv[lane];

    int start = rp[node];
    int d = deg[node];

    float m = -INFINITY, den = 0.f, acc = 0.f;
    for (int i = 0; i < d; i += 8) {
        int sidx[8];
        #pragma unroll
        for (int j = 0; j < 8; j++) {
            int idx = (i + j < d) ? (start + i + j) : start;
            sidx[j] = col[idx];
        }
        float v[8];
        #pragma unroll
        for (int j = 0; j < 8; j++)
            v[j] = xl[(size_t)sidx[j] * 64 + lane];

        float p[8];
        #pragma unroll
        for (int j = 0; j < 8; j++) {
            float s = v[j] + xr_d;
            s = fmaxf(s, SLOPE * s);      // leaky_relu (slope < 1)
            float q = s * a_l;
            q = DPP_ADD(q, 0xB1);         // xor1
            q = DPP_ADD(q, 0x4E);         // xor2   -> quad sums
            q = DPP_ADD(q, 0x141);        // half_mirror: quad0<->1, 2<->3
            q = DPP_ADD(q, 0x140);        // mirror: completes 16-lane sum
            p[j] = (i + j < d) ? q : -INFINITY;
        }

        float bmax = fmaxf(fmaxf(fmaxf(p[0], p[1]), fmaxf(p[2], p[3])),
                           fmaxf(fmaxf(p[4], p[5]), fmaxf(p[6], p[7])));
        float mnew = fmaxf(m, bmax);
        float scale = exp2f(m - mnew);    // first batch: exp2(-inf)=0
        float wsum = 0.f, axsum = 0.f;
        #pragma unroll
        for (int j = 0; j < 8; j++) {
            float w = exp2f(p[j] - mnew); // invalid edge: exp2(-inf)=0
            wsum += w;
            axsum += w * v[j];
        }
        den = den * scale + wsum;
        acc = acc * scale + axsum;
        m = mnew;
    }
    float o = acc / (den + 1e-16f) + b_l;
    if (relu) o = fmaxf(o, 0.f);
    outp[(size_t)node * 64 + lane] = o;
}

// ---------------- launcher ----------------

extern "C" void kernel_launch(void* const* d_in, const int* in_sizes, int n_in,
                              void* d_out, int out_size, void* d_ws, size_t ws_size,
                              hipStream_t stream) {
    const float* x = (const float*)d_in[0];
    const int* ei = (const int*)d_in[1];
    int N = in_sizes[0] / 64;
    int E = in_sizes[1] / 2;

    const float* Wl[3] = {(const float*)d_in[2], (const float*)d_in[6], (const float*)d_in[10]};
    const float* Wr[3] = {(const float*)d_in[3], (const float*)d_in[7], (const float*)d_in[11]};
    const float* Av[3] = {(const float*)d_in[4], (const float*)d_in[8], (const float*)d_in[12]};
    const float* Bv[3] = {(const float*)d_in[5], (const float*)d_in[9], (const float*)d_in[13]};

    char* w = (char*)d_ws;
    auto carve = [&](size_t bytes) {
        void* p = (void*)w;
        w += (bytes + 255) & ~(size_t)255;
        return p;
    };
    float* xl  = (float*)carve((size_t)N * 64 * 4);
    float* xr  = (float*)carve((size_t)N * 64 * 4);
    float* h   = (float*)carve((size_t)N * 64 * 4);
    int*   rp  = (int*)carve((size_t)N * 4);
    int*   deg = (int*)carve((size_t)N * 4);
    int*   cur = (int*)carve((size_t)N * 4);
    int*   col = (int*)carve((size_t)E * 4);
    int*   blk = (int*)carve(256 * 4);

    int nblk1024 = (N + 1023) / 1024;
    int e4_grid = ((E + 3) / 4 + 255) / 256;

    hipMemsetAsync(deg, 0, (size_t)N * 4, stream);
    k_count<<<e4_grid, 256, 0, stream>>>(ei, deg, E);
    k_scan1<<<nblk1024, 256, 0, stream>>>(deg, rp, blk, N);
    k_scan2<<<1, 256, 0, stream>>>(blk, nblk1024);
    k_scan3<<<nblk1024, 256, 0, stream>>>(rp, blk, cur, N);
    k_scatter<<<e4_grid, 256, 0, stream>>>(ei, cur, col, E);

    int gemm_grid = (N + 127) / 128;
    int node_grid = (N + 3) / 4;

    const float* in_l = x;
    for (int l = 0; l < 3; l++) {
        float* out_l = (l == 2) ? (float*)d_out : h;
        int relu = (l < 2) ? 1 : 0;
        k_gemm<<<gemm_grid, 256, 0, stream>>>(in_l, Wl[l], Wr[l], xl, xr, N);
        k_node<<<node_grid, 256, 0, stream>>>(xl, xr, rp, deg, col, Av[l], Bv[l],
                                              out_l, N, relu);
        in_l = h;
    }
}

// Round 8
// 485.847 us; speedup vs baseline: 6.6145x; 1.1198x over previous
//
#include <hip/hip_runtime.h>
#include <math.h>

#define SLOPE 0.2f
#define LOG2E 1.4426950408889634f

// DPP add over 16-lane head group: quad_perm xor1/xor2, row_half_mirror, row_mirror.
#define DPP_ADD(x, ctrl) \
    ((x) + __int_as_float(__builtin_amdgcn_update_dpp( \
        0, __float_as_int(x), (ctrl), 0xF, 0xF, true)))

// ---------------- fused: layer-1 GEMM + degree count (independent work) -------
// blocks [0, gemm_nb): xl/xr = in @ Wl/Wr  (128 rows x 128 cols per block)
// blocks [gemm_nb, ...): deg histogram; rank[e] = atomicAdd(&deg[dst],1)
// (rank makes the placement pass atomic-free: pos = rp[dst] + rank[e].)

__device__ __forceinline__ void gemm_body(const float* __restrict__ in,
                                          const float* __restrict__ Wl,
                                          const float* __restrict__ Wr,
                                          float* __restrict__ xl,
                                          float* __restrict__ xr, int n,
                                          int blk) {
    __shared__ float4 sW[64 * 32];  // [k][jg]: jg<16 -> Wl cols, else Wr
    int t = threadIdx.x;
    for (int i = t; i < 2048; i += 256) {
        int k = i >> 5, jg = i & 31;
        const float* src = (jg < 16) ? (Wl + k * 64 + jg * 4)
                                     : (Wr + k * 64 + (jg - 16) * 4);
        sW[i] = *(const float4*)src;
    }
    __syncthreads();

    int rt = t & 31;   // 32 row tiles of 4 rows
    int ct = t >> 5;   // 8 col tiles of 16 cols (4 jg)
    int row0 = blk * 128 + rt * 4;

    const float* rb[4];
    #pragma unroll
    for (int r = 0; r < 4; r++) {
        int rr = row0 + r;
        if (rr > n - 1) rr = n - 1;   // clamp: always-valid load, no UB
        rb[r] = in + (size_t)rr * 64;
    }

    float4 acc[4][4];
    #pragma unroll
    for (int r = 0; r < 4; r++)
        #pragma unroll
        for (int j = 0; j < 4; j++) acc[r][j] = make_float4(0.f, 0.f, 0.f, 0.f);

    auto compute = [&](const float4 (&xv)[4], int k0) {
        #pragma unroll
        for (int kk = 0; kk < 4; kk++) {
            #pragma unroll
            for (int j = 0; j < 4; j++) {
                float4 w = sW[(k0 + kk) * 32 + ct * 4 + j];
                #pragma unroll
                for (int r = 0; r < 4; r++) {
                    float xk = (kk == 0) ? xv[r].x : (kk == 1) ? xv[r].y
                             : (kk == 2) ? xv[r].z : xv[r].w;
                    acc[r][j].x += xk * w.x;
                    acc[r][j].y += xk * w.y;
                    acc[r][j].z += xk * w.z;
                    acc[r][j].w += xk * w.w;
                }
            }
        }
    };

    float4 xv[4];
    #pragma unroll
    for (int r = 0; r < 4; r++) xv[r] = *(const float4*)(rb[r]);
    #pragma unroll 1
    for (int k0 = 0; k0 < 60; k0 += 4) {
        float4 xn[4];
        #pragma unroll
        for (int r = 0; r < 4; r++) xn[r] = *(const float4*)(rb[r] + k0 + 4);
        compute(xv, k0);
        #pragma unroll
        for (int r = 0; r < 4; r++) xv[r] = xn[r];
    }
    compute(xv, 60);

    #pragma unroll
    for (int r = 0; r < 4; r++) {
        int row = row0 + r;
        if (row < n) {
            #pragma unroll
            for (int j = 0; j < 4; j++) {
                int jg = ct * 4 + j;
                float* dst = (jg < 16) ? (xl + (size_t)row * 64 + jg * 4)
                                       : (xr + (size_t)row * 64 + (jg - 16) * 4);
                *(float4*)dst = acc[r][j];
            }
        }
    }
}

__device__ __forceinline__ void count_body(const int* __restrict__ ei,
                                           int* __restrict__ deg,
                                           int* __restrict__ rank, int E,
                                           int blk) {
    int base = (blk * 256 + threadIdx.x) * 4;
    if (base + 3 < E) {
        int4 d4 = *(const int4*)(ei + E + base);
        int4 r4;
        r4.x = atomicAdd(&deg[d4.x], 1);
        r4.y = atomicAdd(&deg[d4.y], 1);
        r4.z = atomicAdd(&deg[d4.z], 1);
        r4.w = atomicAdd(&deg[d4.w], 1);
        *(int4*)(rank + base) = r4;
    } else {
        for (int e = base; e < E; e++)
            rank[e] = atomicAdd(&deg[ei[E + e]], 1);
    }
}

__global__ __launch_bounds__(256) void k_gemm_count(
        const float* __restrict__ in, const float* __restrict__ Wl,
        const float* __restrict__ Wr, float* __restrict__ xl,
        float* __restrict__ xr, int n,
        const int* __restrict__ ei, int* __restrict__ deg,
        int* __restrict__ rank, int E, int gemm_nb) {
    if ((int)blockIdx.x < gemm_nb)
        gemm_body(in, Wl, Wr, xl, xr, n, blockIdx.x);
    else
        count_body(ei, deg, rank, E, blockIdx.x - gemm_nb);
}

// plain GEMM for layers 2/3
__global__ __launch_bounds__(256) void k_gemm(const float* __restrict__ in,
                                              const float* __restrict__ Wl,
                                              const float* __restrict__ Wr,
                                              float* __restrict__ xl,
                                              float* __restrict__ xr, int n) {
    gemm_body(in, Wl, Wr, xl, xr, n, blockIdx.x);
}

// ---------------- scans (exclusive prefix of deg -> rp) ----------------

__global__ __launch_bounds__(256) void k_scan1(const int* __restrict__ deg,
                                               int* __restrict__ rp,
                                               int* __restrict__ blk, int n) {
    __shared__ int sd[256];
    int t = threadIdx.x;
    int base = blockIdx.x * 1024 + t * 4;
    int v0 = 0, v1 = 0, v2 = 0, v3 = 0;
    if (base + 0 < n) v0 = deg[base + 0];
    if (base + 1 < n) v1 = deg[base + 1];
    if (base + 2 < n) v2 = deg[base + 2];
    if (base + 3 < n) v3 = deg[base + 3];
    int s = v0 + v1 + v2 + v3;
    sd[t] = s;
    __syncthreads();
    for (int off = 1; off < 256; off <<= 1) {
        int x = (t >= off) ? sd[t - off] : 0;
        __syncthreads();
        sd[t] += x;
        __syncthreads();
    }
    int ex = sd[t] - s;
    if (t == 255) blk[blockIdx.x] = sd[255];
    if (base + 0 < n) rp[base + 0] = ex; ex += v0;
    if (base + 1 < n) rp[base + 1] = ex; ex += v1;
    if (base + 2 < n) rp[base + 2] = ex; ex += v2;
    if (base + 3 < n) rp[base + 3] = ex;
}

__global__ __launch_bounds__(256) void k_scan2(int* __restrict__ blk, int nblk) {
    __shared__ int sd[256];
    int t = threadIdx.x;
    int v = (t < nblk) ? blk[t] : 0;
    sd[t] = v;
    __syncthreads();
    for (int off = 1; off < 256; off <<= 1) {
        int x = (t >= off) ? sd[t - off] : 0;
        __syncthreads();
        sd[t] += x;
        __syncthreads();
    }
    if (t < nblk) blk[t] = sd[t] - v;
}

__global__ __launch_bounds__(256) void k_scan3(int* __restrict__ rp,
                                               const int* __restrict__ blk,
                                               int n) {
    int t = threadIdx.x;
    int base = blockIdx.x * 1024 + t * 4;
    int off = blk[blockIdx.x];
    #pragma unroll
    for (int i = 0; i < 4; i++) {
        int idx = base + i;
        if (idx < n) rp[idx] += off;
    }
}

// ---------------- placement: col[rp[dst] + rank] = src (NO atomics) ----------

__global__ __launch_bounds__(256) void k_place(const int* __restrict__ ei,
                                               const int* __restrict__ rp,
                                               const int* __restrict__ rank,
                                               int* __restrict__ col, int E) {
    int base = (blockIdx.x * 256 + threadIdx.x) * 4;
    if (base + 3 < E) {
        int4 s4 = *(const int4*)(ei + base);
        int4 d4 = *(const int4*)(ei + E + base);
        int4 r4 = *(const int4*)(rank + base);
        int p0 = rp[d4.x] + r4.x;
        int p1 = rp[d4.y] + r4.y;
        int p2 = rp[d4.z] + r4.z;
        int p3 = rp[d4.w] + r4.w;
        col[p0] = s4.x;
        col[p1] = s4.y;
        col[p2] = s4.z;
        col[p3] = s4.w;
    } else {
        for (int e = base; e < E; e++)
            col[rp[ei[E + e]] + rank[e]] = ei[e];
    }
}

// ---------------- node kernel: batch-max online-softmax GATv2 ----------------

__global__ __launch_bounds__(256) void k_node(const float* __restrict__ xl,
                                              const float* __restrict__ xr,
                                              const int* __restrict__ rp,
                                              const int* __restrict__ deg,
                                              const int* __restrict__ col,
                                              const float* __restrict__ A,
                                              const float* __restrict__ Bv,
                                              float* __restrict__ outp,
                                              int n, int relu) {
    int lane = threadIdx.x & 63;
    int node = blockIdx.x * 4 + (threadIdx.x >> 6);
    if (node >= n) return;

    float xr_d = xr[(size_t)node * 64 + lane];
    float a_l = A[lane] * LOG2E;
    float b_l = Bv[lane];

    int start = rp[node];
    int d = deg[node];

    float m = -INFINITY, den = 0.f, acc = 0.f;
    for (int i = 0; i < d; i += 8) {
        int sidx[8];
        #pragma unroll
        for (int j = 0; j < 8; j++) {
            int idx = (i + j < d) ? (start + i + j) : start;
            sidx[j] = col[idx];
        }
        float v[8];
        #pragma unroll
        for (int j = 0; j < 8; j++)
            v[j] = xl[(size_t)sidx[j] * 64 + lane];

        float p[8];
        #pragma unroll
        for (int j = 0; j < 8; j++) {
            float s = v[j] + xr_d;
            s = fmaxf(s, SLOPE * s);      // leaky_relu (slope < 1)
            float q = s * a_l;
            q = DPP_ADD(q, 0xB1);         // xor1
            q = DPP_ADD(q, 0x4E);         // xor2   -> quad sums
            q = DPP_ADD(q, 0x141);        // half_mirror
            q = DPP_ADD(q, 0x140);        // mirror -> full 16-lane sum
            p[j] = (i + j < d) ? q : -INFINITY;
        }

        float bmax = fmaxf(fmaxf(fmaxf(p[0], p[1]), fmaxf(p[2], p[3])),
                           fmaxf(fmaxf(p[4], p[5]), fmaxf(p[6], p[7])));
        float mnew = fmaxf(m, bmax);
        float scale = exp2f(m - mnew);    // first batch: exp2(-inf)=0
        float wsum = 0.f, axsum = 0.f;
        #pragma unroll
        for (int j = 0; j < 8; j++) {
            float w = exp2f(p[j] - mnew); // invalid edge: exp2(-inf)=0
            wsum += w;
            axsum += w * v[j];
        }
        den = den * scale + wsum;
        acc = acc * scale + axsum;
        m = mnew;
    }
    float o = acc / (den + 1e-16f) + b_l;
    if (relu) o = fmaxf(o, 0.f);
    outp[(size_t)node * 64 + lane] = o;
}

// ---------------- launcher ----------------

extern "C" void kernel_launch(void* const* d_in, const int* in_sizes, int n_in,
                              void* d_out, int out_size, void* d_ws, size_t ws_size,
                              hipStream_t stream) {
    const float* x = (const float*)d_in[0];
    const int* ei = (const int*)d_in[1];
    int N = in_sizes[0] / 64;
    int E = in_sizes[1] / 2;

    const float* Wl[3] = {(const float*)d_in[2], (const float*)d_in[6], (const float*)d_in[10]};
    const float* Wr[3] = {(const float*)d_in[3], (const float*)d_in[7], (const float*)d_in[11]};
    const float* Av[3] = {(const float*)d_in[4], (const float*)d_in[8], (const float*)d_in[12]};
    const float* Bv[3] = {(const float*)d_in[5], (const float*)d_in[9], (const float*)d_in[13]};

    char* w = (char*)d_ws;
    auto carve = [&](size_t bytes) {
        void* p = (void*)w;
        w += (bytes + 255) & ~(size_t)255;
        return p;
    };
    float* xl   = (float*)carve((size_t)N * 64 * 4);
    float* xr   = (float*)carve((size_t)N * 64 * 4);
    float* h    = (float*)carve((size_t)N * 64 * 4);
    int*   rp   = (int*)carve((size_t)N * 4);
    int*   deg  = (int*)carve((size_t)N * 4);
    int*   rank = (int*)carve((size_t)E * 4);
    int*   col  = (int*)carve((size_t)E * 4);
    int*   blk  = (int*)carve(256 * 4);

    int nblk1024 = (N + 1023) / 1024;
    int e4_grid = ((E + 3) / 4 + 255) / 256;
    int gemm_grid = (N + 127) / 128;
    int node_grid = (N + 3) / 4;

    hipMemsetAsync(deg, 0, (size_t)N * 4, stream);

    // layer-1 GEMM fused with degree count (independent upstream work)
    k_gemm_count<<<gemm_grid + e4_grid, 256, 0, stream>>>(
        x, Wl[0], Wr[0], xl, xr, N, ei, deg, rank, E, gemm_grid);
    k_scan1<<<nblk1024, 256, 0, stream>>>(deg, rp, blk, N);
    k_scan2<<<1, 256, 0, stream>>>(blk, nblk1024);
    k_scan3<<<nblk1024, 256, 0, stream>>>(rp, blk, N);
    k_place<<<e4_grid, 256, 0, stream>>>(ei, rp, rank, col, E);

    const float* in_l = x;
    for (int l = 0; l < 3; l++) {
        float* out_l = (l == 2) ? (float*)d_out : h;
        int relu = (l < 2) ? 1 : 0;
        if (l > 0)
            k_gemm<<<gemm_grid, 256, 0, stream>>>(in_l, Wl[l], Wr[l], xl, xr, N);
        k_node<<<node_grid, 256, 0, stream>>>(xl, xr, rp, deg, col, Av[l], Bv[l],
                                              out_l, N, relu);
        in_l = h;
    }
}